// Round 23
// baseline (211.000 us; speedup 1.0000x reference)
//
#include <hip/hip_runtime.h>
#include <hip/hip_bf16.h>

typedef __attribute__((ext_vector_type(8))) __bf16 bf16x8;
typedef __attribute__((ext_vector_type(8))) unsigned short us8;
typedef __attribute__((ext_vector_type(4))) float f32x4;
typedef __attribute__((ext_vector_type(16))) float f32x16;
typedef __attribute__((ext_vector_type(2))) unsigned int uint2v;

#define N_TOK 8192
#define EMB 1024
#define SC2F 0.18033688011112042f   // 1/sqrt(64) * log2(e), folded into Q projection

static __device__ __forceinline__ unsigned short f2bf(float f) {
  union { __bf16 b; unsigned short u; } c;
  c.b = (__bf16)f;
  return c.u;
}

static __device__ __forceinline__ f32x4 mfma16(bf16x8 a, bf16x8 b, f32x4 c) {
  return __builtin_amdgcn_mfma_f32_16x16x32_bf16(a, b, c, 0, 0, 0);
}
static __device__ __forceinline__ f32x16 mfma32(bf16x8 a, bf16x8 b, f32x16 c) {
  return __builtin_amdgcn_mfma_f32_32x32x16_bf16(a, b, c, 0, 0, 0);
}
static __device__ __forceinline__ unsigned int cvtpk(float lo, float hi) {
  unsigned int r;
  asm("v_cvt_pk_bf16_f32 %0, %1, %2" : "=v"(r) : "v"(lo), "v"(hi));
  return r;
}
// async global->LDS, 16B per lane. LDS dest = wave-uniform base + lane*16.
static __device__ __forceinline__ void gload16(const unsigned short* g, unsigned short* l) {
  __builtin_amdgcn_global_load_lds(
      (const __attribute__((address_space(1))) unsigned int*)g,
      (__attribute__((address_space(3))) unsigned int*)l, 16, 0, 0);
}

// ---------------- fp32 -> bf16 conversion: 3 X inputs + 4 weights ----------------
__global__ __launch_bounds__(256) void convall(
    const float* __restrict__ X0, const float* __restrict__ X1, const float* __restrict__ X2,
    const float* __restrict__ W0, const float* __restrict__ W1,
    const float* __restrict__ W2, const float* __restrict__ W3,
    unsigned short* __restrict__ Dq, unsigned short* __restrict__ Dk,
    unsigned short* __restrict__ Dv, unsigned short* __restrict__ Wb)
{
  const int bid = blockIdx.x;
  const float* src;
  unsigned short* dst;
  long base;
  if (bid < 6144) {
    const int t = bid >> 11;
    const int b = bid & 2047;
    src = (t == 0) ? X0 : (t == 1) ? X1 : X2;
    dst = (t == 0) ? Dq : (t == 1) ? Dk : Dv;
    base = ((long)b * 256 + threadIdx.x) * 16;
  } else {
    const int r = bid - 6144;
    const int t = r >> 8;
    const int b = r & 255;
    src = (t == 0) ? W0 : (t == 1) ? W1 : (t == 2) ? W2 : W3;
    dst = Wb + (size_t)t * EMB * EMB;
    base = ((long)b * 256 + threadIdx.x) * 16;
  }
  float4 f0 = *(const float4*)(src + base);
  float4 f1 = *(const float4*)(src + base + 4);
  float4 f2 = *(const float4*)(src + base + 8);
  float4 f3 = *(const float4*)(src + base + 12);
  us8 p0, p1;
  p0[0]=f2bf(f0.x); p0[1]=f2bf(f0.y); p0[2]=f2bf(f0.z); p0[3]=f2bf(f0.w);
  p0[4]=f2bf(f1.x); p0[5]=f2bf(f1.y); p0[6]=f2bf(f1.z); p0[7]=f2bf(f1.w);
  p1[0]=f2bf(f2.x); p1[1]=f2bf(f2.y); p1[2]=f2bf(f2.z); p1[3]=f2bf(f2.w);
  p1[4]=f2bf(f3.x); p1[5]=f2bf(f3.y); p1[6]=f2bf(f3.z); p1[7]=f2bf(f3.w);
  *(us8*)(dst + base)     = p0;
  *(us8*)(dst + base + 8) = p1;
}

// ---------------- fused QKV projection: m97 structure + z=2 operand-swap ----------------
// z=0 (Q) output pre-scaled by SC2F: attention computes exp2(score) directly.
__global__ __launch_bounds__(256) void qkv_gemm7(
    const unsigned short* __restrict__ Xq, const unsigned short* __restrict__ Xk,
    const unsigned short* __restrict__ Xv, const unsigned short* __restrict__ Wb,
    const float* __restrict__ bq, const float* __restrict__ bk, const float* __restrict__ bv,
    unsigned short* __restrict__ O0, unsigned short* __restrict__ O1, unsigned short* __restrict__ O2)
{
  __shared__ __align__(16) unsigned short As[128 * 32];
  __shared__ __align__(16) unsigned short Bs[128 * 32];

  const int z = blockIdx.z;
  const unsigned short* X = (z == 0) ? Xq : (z == 1) ? Xk : Xv;
  const unsigned short* W = Wb + (size_t)z * EMB * EMB;
  const float* bias = (z == 0) ? bq : (z == 1) ? bk : bv;

  const int lin  = blockIdx.x;
  const int work = (lin & 7) * 64 + (lin >> 3);
  const long brow = (long)(work >> 3) * 128;
  const long bcol = (long)(work & 7) * 128;

  const int tid  = threadIdx.x;
  const int lane = tid & 63;
  const int w    = tid >> 6;
  const int wrb  = (w >> 1) * 64;
  const int wcb  = (w & 1) * 64;
  const int r16  = lane & 15;
  const int kq   = (lane >> 4) * 8;
  const int rq   = (lane >> 4) * 4;

  const int srow = lane >> 2;
  const int scol = (lane & 3) * 8;
  const unsigned short* Ag0 = X + (brow + w*32      + srow) * (long)EMB + scol;
  const unsigned short* Ag1 = X + (brow + w*32 + 16 + srow) * (long)EMB + scol;
  const unsigned short* Bg0 = W + (bcol + w*32      + srow) * (long)EMB + scol;
  const unsigned short* Bg1 = W + (bcol + w*32 + 16 + srow) * (long)EMB + scol;
  unsigned short* Al0 = As + w * 1024;
  unsigned short* Al1 = As + w * 1024 + 512;
  unsigned short* Bl0 = Bs + w * 1024;
  unsigned short* Bl1 = Bs + w * 1024 + 512;

  const f32x4 zz = {0.f, 0.f, 0.f, 0.f};
  f32x4 acc[4][4];
#pragma unroll
  for (int i = 0; i < 4; ++i)
#pragma unroll
    for (int j = 0; j < 4; ++j) acc[i][j] = zz;

  for (int k0 = 0; k0 < EMB; k0 += 32) {
    __syncthreads();
    gload16(Ag0 + k0, Al0);
    gload16(Ag1 + k0, Al1);
    gload16(Bg0 + k0, Bl0);
    gload16(Bg1 + k0, Bl1);
    __syncthreads();

    bf16x8 av[4], bv_[4];
#pragma unroll
    for (int mi = 0; mi < 4; ++mi) av[mi]  = *(const bf16x8*)&As[(wrb + mi*16 + r16)*32 + kq];
#pragma unroll
    for (int ni = 0; ni < 4; ++ni) bv_[ni] = *(const bf16x8*)&Bs[(wcb + ni*16 + r16)*32 + kq];
    if (z == 2) {
#pragma unroll
      for (int mi = 0; mi < 4; ++mi)
#pragma unroll
        for (int ni = 0; ni < 4; ++ni)
          acc[mi][ni] = mfma16(bv_[ni], av[mi], acc[mi][ni]);   // swapped: D-col = token
    } else {
#pragma unroll
      for (int mi = 0; mi < 4; ++mi)
#pragma unroll
        for (int ni = 0; ni < 4; ++ni)
          acc[mi][ni] = mfma16(av[mi], bv_[ni], acc[mi][ni]);
    }
  }

  if (z == 2) {
#pragma unroll
    for (int ni = 0; ni < 4; ++ni)
#pragma unroll
      for (int jr = 0; jr < 4; ++jr) {
        const long c = bcol + wcb + ni*16 + rq + jr;
        const float bval = bias[c];
#pragma unroll
        for (int mi = 0; mi < 4; ++mi) {
          long rt = brow + wrb + mi*16 + r16;
          if (c >= 512) {
            const long seg = rt >> 12;
            const long pp = rt & 4095;
            rt = (seg << 12) + ((pp & 1) ? (pp >> 1) : 2048 + (pp >> 1));
          }
          O2[c * (long)N_TOK + rt] = f2bf(acc[mi][ni][jr] + bval);
        }
      }
  } else {
    unsigned short* O = (z == 0) ? O0 : O1;
#pragma unroll
    for (int ni = 0; ni < 4; ++ni) {
      const long col = bcol + wcb + ni*16 + r16;
      const float bval = bias[col];
#pragma unroll
      for (int mi = 0; mi < 4; ++mi)
#pragma unroll
        for (int jr = 0; jr < 4; ++jr) {
          const long row = brow + wrb + mi*16 + rq + jr;
          float v = acc[mi][ni][jr] + bval;
          if (z == 0) v *= SC2F;          // fold softmax scale into Q
          O[row * (long)EMB + col] = f2bf(v);
        }
    }
  }
}

// ---------------- dilated flash attention: R21 + fused even-token zeroing ----------------
// Steady loop branch/mask-free; diag tile peeled. Group-1 blocks also zero the
// even-token row (qrow-1) for their head columns in the epilogue, replacing the
// separate zerog1 dispatch (coverage: all 4096 even tokens x cols 512..1023).
__global__ __launch_bounds__(128) void attn_dilated14(
    const unsigned short* __restrict__ Qp, const unsigned short* __restrict__ Kp,
    const unsigned short* __restrict__ Vt, unsigned short* __restrict__ AO)
{
  __shared__ __align__(16) unsigned short Ks[2][64][76];
  __shared__ __align__(16) unsigned short Vs[2][64][76];   // Vs[buf][d][key]

  const int z   = blockIdx.z;
  const int g1  = (z >= 4);
  const int dil = g1 ? 2 : 1;
  const int off = g1 ? 1 : 0;
  const long segb = g1 ? (long)(z - 4) * 4096 : (long)z * 2048;
  const int h   = (g1 ? 8 : 0) + blockIdx.y;
  const int h64 = h * 64;

  const int bx   = (int)blockIdx.x;   // 0..15
  const int tid  = threadIdx.x;       // 0..127
  const int lane = tid & 63;
  const int w    = tid >> 6;          // wave 0/1: rows w*32..w*32+31 of the half
  const int q5   = lane & 31;
  const int hh   = lane >> 5;

  const int srow = tid >> 1;
  const int sc   = (tid & 1) * 32;

#pragma unroll
  for (int ph = 0; ph < 2; ++ph) {
    const int hf = ph ? bx : 31 - bx;   // half-tile index 0..31 (paired, equal work)
    const int qq = hf*64 + w*32 + q5;
    const long qrow = segb + off + (long)dil * qq;

    bf16x8 qf[4];
    {
      const unsigned short* qsrc = Qp + qrow * EMB + h64 + 8*hh;
#pragma unroll
      for (int s = 0; s < 4; ++s) qf[s] = *(const bf16x8*)(qsrc + 16*s);
    }

    float l_run = 0.f;
    f32x16 o0, o1;
#pragma unroll
    for (int r = 0; r < 16; ++r) { o0[r] = 0.f; o1[r] = 0.f; }

    us8 kr0, kr1, kr2, kr3, vr0, vr1, vr2, vr3;
    // prologue: stage tile 0
    {
      const long gk = segb + off + (long)dil * srow;
      const unsigned short* ksrc = Kp + gk*EMB + h64 + sc;
      kr0 = *(const us8*)ksrc;        kr1 = *(const us8*)(ksrc + 8);
      kr2 = *(const us8*)(ksrc + 16); kr3 = *(const us8*)(ksrc + 24);
      const unsigned short* vsrc = Vt + (long)(h64 + srow)*N_TOK + segb + sc;
      vr0 = *(const us8*)vsrc;        vr1 = *(const us8*)(vsrc + 8);
      vr2 = *(const us8*)(vsrc + 16); vr3 = *(const us8*)(vsrc + 24);
      *(us8*)&Ks[0][srow][sc]    = kr0; *(us8*)&Ks[0][srow][sc+8]  = kr1;
      *(us8*)&Ks[0][srow][sc+16] = kr2; *(us8*)&Ks[0][srow][sc+24] = kr3;
      *(us8*)&Vs[0][srow][sc]    = vr0; *(us8*)&Vs[0][srow][sc+8]  = vr1;
      *(us8*)&Vs[0][srow][sc+16] = vr2; *(us8*)&Vs[0][srow][sc+24] = vr3;
    }
    __syncthreads();
    int cur = 0;

    // ---- steady loop: tiles 0..hf-1, branch/mask-free ----
    for (int j = 0; j < hf; ++j) {
      // issue next-tile loads early (latency hides under compute)
      {
        const long gk = segb + off + (long)dil * ((j+1)*64 + srow);
        const unsigned short* ksrc = Kp + gk*EMB + h64 + sc;
        kr0 = *(const us8*)ksrc;        kr1 = *(const us8*)(ksrc + 8);
        kr2 = *(const us8*)(ksrc + 16); kr3 = *(const us8*)(ksrc + 24);
        const unsigned short* vsrc = Vt + (long)(h64 + srow)*N_TOK + segb + (j+1)*64 + sc;
        vr0 = *(const us8*)vsrc;        vr1 = *(const us8*)(vsrc + 8);
        vr2 = *(const us8*)(vsrc + 16); vr3 = *(const us8*)(vsrc + 24);
      }

      f32x16 sa0, sa1;
#pragma unroll
      for (int r = 0; r < 16; ++r) { sa0[r] = 0.f; sa1[r] = 0.f; }
      __builtin_amdgcn_s_setprio(1);
#pragma unroll
      for (int s = 0; s < 4; ++s) {
        bf16x8 ka = *(const bf16x8*)&Ks[cur][q5][16*s + 8*hh];
        sa0 = mfma32(ka, qf[s], sa0);
      }
#pragma unroll
      for (int s = 0; s < 4; ++s) {
        bf16x8 kb = *(const bf16x8*)&Ks[cur][32 + q5][16*s + 8*hh];
        sa1 = mfma32(kb, qf[s], sa1);
      }
      __builtin_amdgcn_s_setprio(0);

      float sv[32];
#pragma unroll
      for (int r = 0; r < 16; ++r) { sv[r] = sa0[r]; sv[16+r] = sa1[r]; }

      float ps0 = 0.f, ps1 = 0.f, ps2 = 0.f, ps3 = 0.f;
#pragma unroll
      for (int i = 0; i < 32; i += 4) {
        float e0 = exp2f(sv[i]);   sv[i]   = e0; ps0 += e0;
        float e1 = exp2f(sv[i+1]); sv[i+1] = e1; ps1 += e1;
        float e2 = exp2f(sv[i+2]); sv[i+2] = e2; ps2 += e2;
        float e3 = exp2f(sv[i+3]); sv[i+3] = e3; ps3 += e3;
      }
      float psum = (ps0 + ps1) + (ps2 + ps3);
      {
        union { float f; unsigned int u; } pc; pc.f = psum;
        uint2v ps = __builtin_amdgcn_permlane32_swap(pc.u, pc.u, false, false);
        union { unsigned int u; float f; } a0, a1;
        a0.u = ps[0]; a1.u = ps[1];
        psum = a0.f + a1.f;
      }
      l_run += psum;

#pragma unroll
      for (int ks = 0; ks < 4; ++ks) {
        const unsigned int pk0 = cvtpk(sv[8*ks+0], sv[8*ks+1]);
        const unsigned int pk1 = cvtpk(sv[8*ks+2], sv[8*ks+3]);
        const unsigned int pk2 = cvtpk(sv[8*ks+4], sv[8*ks+5]);
        const unsigned int pk3 = cvtpk(sv[8*ks+6], sv[8*ks+7]);
        uint2v s02 = __builtin_amdgcn_permlane32_swap(pk0, pk2, false, false);
        uint2v s13 = __builtin_amdgcn_permlane32_swap(pk1, pk3, false, false);
        union { unsigned int wd[4]; bf16x8 v; } pu;
        pu.wd[0] = s02[0];
        pu.wd[1] = s13[0];
        pu.wd[2] = s02[1];
        pu.wd[3] = s13[1];
        __builtin_amdgcn_s_setprio(1);
        bf16x8 va = *(const bf16x8*)&Vs[cur][q5][16*ks + 8*hh];
        o0 = mfma32(va, pu.v, o0);
        bf16x8 vb = *(const bf16x8*)&Vs[cur][32 + q5][16*ks + 8*hh];
        o1 = mfma32(vb, pu.v, o1);
        __builtin_amdgcn_s_setprio(0);
      }

      // write-late: next tile into the other buffer
      *(us8*)&Ks[cur^1][srow][sc]    = kr0; *(us8*)&Ks[cur^1][srow][sc+8]  = kr1;
      *(us8*)&Ks[cur^1][srow][sc+16] = kr2; *(us8*)&Ks[cur^1][srow][sc+24] = kr3;
      *(us8*)&Vs[cur^1][srow][sc]    = vr0; *(us8*)&Vs[cur^1][srow][sc+8]  = vr1;
      *(us8*)&Vs[cur^1][srow][sc+16] = vr2; *(us8*)&Vs[cur^1][srow][sc+24] = vr3;
      __syncthreads();
      cur ^= 1;
    }

    // ---- peeled diagonal tile (j == hf), buffer cur ----
    {
      const int j = hf;
      f32x16 sa0, sa1;
#pragma unroll
      for (int r = 0; r < 16; ++r) { sa0[r] = 0.f; sa1[r] = 0.f; }
      __builtin_amdgcn_s_setprio(1);
#pragma unroll
      for (int s = 0; s < 4; ++s) {
        bf16x8 ka = *(const bf16x8*)&Ks[cur][q5][16*s + 8*hh];
        sa0 = mfma32(ka, qf[s], sa0);
      }
#pragma unroll
      for (int s = 0; s < 4; ++s) {
        bf16x8 kb = *(const bf16x8*)&Ks[cur][32 + q5][16*s + 8*hh];
        sa1 = mfma32(kb, qf[s], sa1);
      }
      __builtin_amdgcn_s_setprio(0);

      const bool do_kb1 = (w == 1);

      float sv[32];
#pragma unroll
      for (int r = 0; r < 16; ++r) {
        const int kof = (r&3) + 8*(r>>2);
        float v = sa0[r];
        if (j*64 + kof + 4*hh > qq) v = -1e30f;
        sv[r] = v;
      }
      if (do_kb1) {
#pragma unroll
        for (int r = 0; r < 16; ++r) {
          const int kof = (r&3) + 8*(r>>2);
          float v = sa1[r];
          if (j*64 + 32 + kof + 4*hh > qq) v = -1e30f;
          sv[16+r] = v;
        }
      }

      float ps0 = 0.f, ps1 = 0.f, ps2 = 0.f, ps3 = 0.f;
#pragma unroll
      for (int i = 0; i < 16; i += 4) {
        float e0 = exp2f(sv[i]);   sv[i]   = e0; ps0 += e0;
        float e1 = exp2f(sv[i+1]); sv[i+1] = e1; ps1 += e1;
        float e2 = exp2f(sv[i+2]); sv[i+2] = e2; ps2 += e2;
        float e3 = exp2f(sv[i+3]); sv[i+3] = e3; ps3 += e3;
      }
      if (do_kb1) {
#pragma unroll
        for (int i = 16; i < 32; i += 4) {
          float e0 = exp2f(sv[i]);   sv[i]   = e0; ps0 += e0;
          float e1 = exp2f(sv[i+1]); sv[i+1] = e1; ps1 += e1;
          float e2 = exp2f(sv[i+2]); sv[i+2] = e2; ps2 += e2;
          float e3 = exp2f(sv[i+3]); sv[i+3] = e3; ps3 += e3;
        }
      }
      float psum = (ps0 + ps1) + (ps2 + ps3);
      {
        union { float f; unsigned int u; } pc; pc.f = psum;
        uint2v ps = __builtin_amdgcn_permlane32_swap(pc.u, pc.u, false, false);
        union { unsigned int u; float f; } a0, a1;
        a0.u = ps[0]; a1.u = ps[1];
        psum = a0.f + a1.f;
      }
      l_run += psum;

#pragma unroll
      for (int ks = 0; ks < 4; ++ks) {
        if (ks >= 2 && !do_kb1) continue;
        const unsigned int pk0 = cvtpk(sv[8*ks+0], sv[8*ks+1]);
        const unsigned int pk1 = cvtpk(sv[8*ks+2], sv[8*ks+3]);
        const unsigned int pk2 = cvtpk(sv[8*ks+4], sv[8*ks+5]);
        const unsigned int pk3 = cvtpk(sv[8*ks+6], sv[8*ks+7]);
        uint2v s02 = __builtin_amdgcn_permlane32_swap(pk0, pk2, false, false);
        uint2v s13 = __builtin_amdgcn_permlane32_swap(pk1, pk3, false, false);
        union { unsigned int wd[4]; bf16x8 v; } pu;
        pu.wd[0] = s02[0];
        pu.wd[1] = s13[0];
        pu.wd[2] = s02[1];
        pu.wd[3] = s13[1];
        __builtin_amdgcn_s_setprio(1);
        bf16x8 va = *(const bf16x8*)&Vs[cur][q5][16*ks + 8*hh];
        o0 = mfma32(va, pu.v, o0);
        bf16x8 vb = *(const bf16x8*)&Vs[cur][32 + q5][16*ks + 8*hh];
        o1 = mfma32(vb, pu.v, o1);
        __builtin_amdgcn_s_setprio(0);
      }
    }
    __syncthreads();   // protect buffer before next phase's prologue staging

    // epilogue for this phase (+ fused even-token zeroing for group 1)
    {
      const float inv = 1.f / l_run;
      unsigned short* dst = AO + qrow * EMB + h64;
      unsigned short* dz  = AO + (qrow - 1) * EMB + h64;   // even-token row (g1 only)
#pragma unroll
      for (int r = 0; r < 16; ++r) {
        const int d = (r&3) + 8*(r>>2) + 4*hh;
        dst[d]      = f2bf(o0[r] * inv);
        dst[32 + d] = f2bf(o1[r] * inv);
        if (g1) { dz[d] = 0; dz[32 + d] = 0; }
      }
    }
  }
}

// ---------------- output projection: m97 structure ----------------
__global__ __launch_bounds__(256) void gemm_out4(
    const unsigned short* __restrict__ A, const unsigned short* __restrict__ Wb,
    const float* __restrict__ bias, float* __restrict__ outp)
{
  __shared__ __align__(16) unsigned short As[128 * 32];
  __shared__ __align__(16) unsigned short Bs[128 * 32];

  const int lin  = blockIdx.x;
  const int work = (lin & 7) * 64 + (lin >> 3);
  const long brow = (long)(work >> 3) * 128;
  const long bcol = (long)(work & 7) * 128;

  const int tid  = threadIdx.x;
  const int lane = tid & 63;
  const int w    = tid >> 6;
  const int wrb  = (w >> 1) * 64;
  const int wcb  = (w & 1) * 64;
  const int r16  = lane & 15;
  const int kq   = (lane >> 4) * 8;
  const int rq   = (lane >> 4) * 4;

  const int srow = lane >> 2;
  const int scol = (lane & 3) * 8;
  const unsigned short* Ag0 = A  + (brow + w*32      + srow) * (long)EMB + scol;
  const unsigned short* Ag1 = A  + (brow + w*32 + 16 + srow) * (long)EMB + scol;
  const unsigned short* Bg0 = Wb + (bcol + w*32      + srow) * (long)EMB + scol;
  const unsigned short* Bg1 = Wb + (bcol + w*32 + 16 + srow) * (long)EMB + scol;
  unsigned short* Al0 = As + w * 1024;
  unsigned short* Al1 = As + w * 1024 + 512;
  unsigned short* Bl0 = Bs + w * 1024;
  unsigned short* Bl1 = Bs + w * 1024 + 512;

  const f32x4 zz = {0.f, 0.f, 0.f, 0.f};
  f32x4 acc[4][4];
#pragma unroll
  for (int i = 0; i < 4; ++i)
#pragma unroll
    for (int j = 0; j < 4; ++j) acc[i][j] = zz;

  for (int k0 = 0; k0 < EMB; k0 += 32) {
    __syncthreads();
    gload16(Ag0 + k0, Al0);
    gload16(Ag1 + k0, Al1);
    gload16(Bg0 + k0, Bl0);
    gload16(Bg1 + k0, Bl1);
    __syncthreads();

    bf16x8 av[4], bv_[4];
#pragma unroll
    for (int mi = 0; mi < 4; ++mi) av[mi]  = *(const bf16x8*)&As[(wrb + mi*16 + r16)*32 + kq];
#pragma unroll
    for (int ni = 0; ni < 4; ++ni) bv_[ni] = *(const bf16x8*)&Bs[(wcb + ni*16 + r16)*32 + kq];
#pragma unroll
    for (int mi = 0; mi < 4; ++mi)
#pragma unroll
      for (int ni = 0; ni < 4; ++ni)
        acc[mi][ni] = mfma16(av[mi], bv_[ni], acc[mi][ni]);
  }

#pragma unroll
  for (int ni = 0; ni < 4; ++ni) {
    const long col = bcol + wcb + ni*16 + r16;
    const float bval = bias[col];
#pragma unroll
    for (int mi = 0; mi < 4; ++mi)
#pragma unroll
      for (int jr = 0; jr < 4; ++jr) {
        const long row = brow + wrb + mi*16 + rq + jr;
        outp[row * (long)EMB + col] = acc[mi][ni][jr] + bval;
      }
  }
}

extern "C" void kernel_launch(void* const* d_in, const int* in_sizes, int n_in,
                              void* d_out, int out_size, void* d_ws, size_t ws_size,
                              hipStream_t stream) {
  const float* query = (const float*)d_in[0];
  const float* key_  = (const float*)d_in[1];
  const float* value = (const float*)d_in[2];
  const float* Wq = (const float*)d_in[3];
  const float* bq = (const float*)d_in[4];
  const float* Wk = (const float*)d_in[5];
  const float* bk = (const float*)d_in[6];
  const float* Wv = (const float*)d_in[7];
  const float* bv = (const float*)d_in[8];
  const float* Wo = (const float*)d_in[9];
  const float* bo = (const float*)d_in[10];

  unsigned short* Qp  = (unsigned short*)d_ws;
  unsigned short* Kp  = Qp + (size_t)N_TOK * EMB;
  unsigned short* Vt  = Kp + (size_t)N_TOK * EMB;   // [EMB][N_TOK], group1 token-remapped
  unsigned short* Wb  = Vt + (size_t)N_TOK * EMB;   // Wq,Wk,Wv,Wo bf16 (8 MB)
  unsigned short* S   = Wb + (size_t)4 * EMB * EMB; // X_v, then AO
  unsigned short* Xbq = (unsigned short*)d_out;     // scratch in d_out
  unsigned short* Xbk = Xbq + (size_t)N_TOK * EMB;
  unsigned short* Xbv = S;
  unsigned short* AO  = S;
  unsigned short* Wob = Wb + (size_t)3 * EMB * EMB;

  dim3 blk(256);

  hipLaunchKernelGGL(convall, dim3(7168), blk, 0, stream,
                     query, key_, value, Wq, Wk, Wv, Wo, Xbq, Xbk, Xbv, Wb);

  hipLaunchKernelGGL(qkv_gemm7, dim3(512, 1, 3), blk, 0, stream,
                     Xbq, Xbk, Xbv, Wb, bq, bk, bv, Qp, Kp, Vt);

  hipLaunchKernelGGL(attn_dilated14, dim3(16, 8, 6), dim3(128), 0, stream, Qp, Kp, Vt, AO);

  hipLaunchKernelGGL(gemm_out4, dim3(512), blk, 0, stream, AO, Wob, bo, (float*)d_out);
}

// Round 24
// 202.552 us; speedup vs baseline: 1.0417x; 1.0417x over previous
//
#include <hip/hip_runtime.h>
#include <hip/hip_bf16.h>

typedef __attribute__((ext_vector_type(8))) __bf16 bf16x8;
typedef __attribute__((ext_vector_type(8))) unsigned short us8;
typedef __attribute__((ext_vector_type(4))) float f32x4;
typedef __attribute__((ext_vector_type(16))) float f32x16;
typedef __attribute__((ext_vector_type(2))) unsigned int uint2v;

#define N_TOK 8192
#define EMB 1024
#define SC2F 0.18033688011112042f   // 1/sqrt(64) * log2(e), folded into Q projection

static __device__ __forceinline__ unsigned short f2bf(float f) {
  union { __bf16 b; unsigned short u; } c;
  c.b = (__bf16)f;
  return c.u;
}

static __device__ __forceinline__ f32x4 mfma16(bf16x8 a, bf16x8 b, f32x4 c) {
  return __builtin_amdgcn_mfma_f32_16x16x32_bf16(a, b, c, 0, 0, 0);
}
static __device__ __forceinline__ f32x16 mfma32(bf16x8 a, bf16x8 b, f32x16 c) {
  return __builtin_amdgcn_mfma_f32_32x32x16_bf16(a, b, c, 0, 0, 0);
}
static __device__ __forceinline__ unsigned int cvtpk(float lo, float hi) {
  unsigned int r;
  asm("v_cvt_pk_bf16_f32 %0, %1, %2" : "=v"(r) : "v"(lo), "v"(hi));
  return r;
}
// async global->LDS, 16B per lane. LDS dest = wave-uniform base + lane*16.
static __device__ __forceinline__ void gload16(const unsigned short* g, unsigned short* l) {
  __builtin_amdgcn_global_load_lds(
      (const __attribute__((address_space(1))) unsigned int*)g,
      (__attribute__((address_space(3))) unsigned int*)l, 16, 0, 0);
}

// ---------------- fp32 -> bf16 conversion: 3 X inputs + 4 weights ----------------
__global__ __launch_bounds__(256) void convall(
    const float* __restrict__ X0, const float* __restrict__ X1, const float* __restrict__ X2,
    const float* __restrict__ W0, const float* __restrict__ W1,
    const float* __restrict__ W2, const float* __restrict__ W3,
    unsigned short* __restrict__ Dq, unsigned short* __restrict__ Dk,
    unsigned short* __restrict__ Dv, unsigned short* __restrict__ Wb)
{
  const int bid = blockIdx.x;
  const float* src;
  unsigned short* dst;
  long base;
  if (bid < 6144) {
    const int t = bid >> 11;
    const int b = bid & 2047;
    src = (t == 0) ? X0 : (t == 1) ? X1 : X2;
    dst = (t == 0) ? Dq : (t == 1) ? Dk : Dv;
    base = ((long)b * 256 + threadIdx.x) * 16;
  } else {
    const int r = bid - 6144;
    const int t = r >> 8;
    const int b = r & 255;
    src = (t == 0) ? W0 : (t == 1) ? W1 : (t == 2) ? W2 : W3;
    dst = Wb + (size_t)t * EMB * EMB;
    base = ((long)b * 256 + threadIdx.x) * 16;
  }
  float4 f0 = *(const float4*)(src + base);
  float4 f1 = *(const float4*)(src + base + 4);
  float4 f2 = *(const float4*)(src + base + 8);
  float4 f3 = *(const float4*)(src + base + 12);
  us8 p0, p1;
  p0[0]=f2bf(f0.x); p0[1]=f2bf(f0.y); p0[2]=f2bf(f0.z); p0[3]=f2bf(f0.w);
  p0[4]=f2bf(f1.x); p0[5]=f2bf(f1.y); p0[6]=f2bf(f1.z); p0[7]=f2bf(f1.w);
  p1[0]=f2bf(f2.x); p1[1]=f2bf(f2.y); p1[2]=f2bf(f2.z); p1[3]=f2bf(f2.w);
  p1[4]=f2bf(f3.x); p1[5]=f2bf(f3.y); p1[6]=f2bf(f3.z); p1[7]=f2bf(f3.w);
  *(us8*)(dst + base)     = p0;
  *(us8*)(dst + base + 8) = p1;
}

// ---------------- selective zero: AO[even token][512..1023] = 0 ----------------
__global__ __launch_bounds__(256) void zerog1(unsigned short* __restrict__ AO)
{
  const int idx = blockIdx.x * 256 + threadIdx.x;
  const int row = idx >> 6;
  const int c8  = (idx & 63) * 8;
  const us8 zz = {0,0,0,0,0,0,0,0};
  *(us8*)(AO + (long)(row * 2) * EMB + 512 + c8) = zz;
}

// ---------------- fused QKV projection: m97 structure + z=2 operand-swap ----------------
__global__ __launch_bounds__(256) void qkv_gemm7(
    const unsigned short* __restrict__ Xq, const unsigned short* __restrict__ Xk,
    const unsigned short* __restrict__ Xv, const unsigned short* __restrict__ Wb,
    const float* __restrict__ bq, const float* __restrict__ bk, const float* __restrict__ bv,
    unsigned short* __restrict__ O0, unsigned short* __restrict__ O1, unsigned short* __restrict__ O2)
{
  __shared__ __align__(16) unsigned short As[128 * 32];
  __shared__ __align__(16) unsigned short Bs[128 * 32];

  const int z = blockIdx.z;
  const unsigned short* X = (z == 0) ? Xq : (z == 1) ? Xk : Xv;
  const unsigned short* W = Wb + (size_t)z * EMB * EMB;
  const float* bias = (z == 0) ? bq : (z == 1) ? bk : bv;

  const int lin  = blockIdx.x;
  const int work = (lin & 7) * 64 + (lin >> 3);
  const long brow = (long)(work >> 3) * 128;
  const long bcol = (long)(work & 7) * 128;

  const int tid  = threadIdx.x;
  const int lane = tid & 63;
  const int w    = tid >> 6;
  const int wrb  = (w >> 1) * 64;
  const int wcb  = (w & 1) * 64;
  const int r16  = lane & 15;
  const int kq   = (lane >> 4) * 8;
  const int rq   = (lane >> 4) * 4;

  const int srow = lane >> 2;
  const int scol = (lane & 3) * 8;
  const unsigned short* Ag0 = X + (brow + w*32      + srow) * (long)EMB + scol;
  const unsigned short* Ag1 = X + (brow + w*32 + 16 + srow) * (long)EMB + scol;
  const unsigned short* Bg0 = W + (bcol + w*32      + srow) * (long)EMB + scol;
  const unsigned short* Bg1 = W + (bcol + w*32 + 16 + srow) * (long)EMB + scol;
  unsigned short* Al0 = As + w * 1024;
  unsigned short* Al1 = As + w * 1024 + 512;
  unsigned short* Bl0 = Bs + w * 1024;
  unsigned short* Bl1 = Bs + w * 1024 + 512;

  const f32x4 zz = {0.f, 0.f, 0.f, 0.f};
  f32x4 acc[4][4];
#pragma unroll
  for (int i = 0; i < 4; ++i)
#pragma unroll
    for (int j = 0; j < 4; ++j) acc[i][j] = zz;

  for (int k0 = 0; k0 < EMB; k0 += 32) {
    __syncthreads();
    gload16(Ag0 + k0, Al0);
    gload16(Ag1 + k0, Al1);
    gload16(Bg0 + k0, Bl0);
    gload16(Bg1 + k0, Bl1);
    __syncthreads();

    bf16x8 av[4], bv_[4];
#pragma unroll
    for (int mi = 0; mi < 4; ++mi) av[mi]  = *(const bf16x8*)&As[(wrb + mi*16 + r16)*32 + kq];
#pragma unroll
    for (int ni = 0; ni < 4; ++ni) bv_[ni] = *(const bf16x8*)&Bs[(wcb + ni*16 + r16)*32 + kq];
    if (z == 2) {
#pragma unroll
      for (int mi = 0; mi < 4; ++mi)
#pragma unroll
        for (int ni = 0; ni < 4; ++ni)
          acc[mi][ni] = mfma16(bv_[ni], av[mi], acc[mi][ni]);   // swapped: D-col = token
    } else {
#pragma unroll
      for (int mi = 0; mi < 4; ++mi)
#pragma unroll
        for (int ni = 0; ni < 4; ++ni)
          acc[mi][ni] = mfma16(av[mi], bv_[ni], acc[mi][ni]);
    }
  }

  if (z == 2) {
#pragma unroll
    for (int ni = 0; ni < 4; ++ni)
#pragma unroll
      for (int jr = 0; jr < 4; ++jr) {
        const long c = bcol + wcb + ni*16 + rq + jr;
        const float bval = bias[c];
#pragma unroll
        for (int mi = 0; mi < 4; ++mi) {
          long rt = brow + wrb + mi*16 + r16;
          if (c >= 512) {
            const long seg = rt >> 12;
            const long pp = rt & 4095;
            rt = (seg << 12) + ((pp & 1) ? (pp >> 1) : 2048 + (pp >> 1));
          }
          O2[c * (long)N_TOK + rt] = f2bf(acc[mi][ni][jr] + bval);
        }
      }
  } else {
    unsigned short* O = (z == 0) ? O0 : O1;
#pragma unroll
    for (int ni = 0; ni < 4; ++ni) {
      const long col = bcol + wcb + ni*16 + r16;
      const float bval = bias[col];
#pragma unroll
      for (int mi = 0; mi < 4; ++mi)
#pragma unroll
        for (int jr = 0; jr < 4; ++jr) {
          const long row = brow + wrb + mi*16 + rq + jr;
          float v = acc[mi][ni][jr] + bval;
          if (z == 0) v *= SC2F;          // fold softmax scale into Q
          O[row * (long)EMB + col] = f2bf(v);
        }
    }
  }
}

// ---------------- dilated flash attention: R18 + peeled diagonal tile ----------------
__global__ __launch_bounds__(128) void attn_dilated12(
    const unsigned short* __restrict__ Qp, const unsigned short* __restrict__ Kp,
    const unsigned short* __restrict__ Vt, unsigned short* __restrict__ AO)
{
  __shared__ __align__(16) unsigned short Ks[2][64][76];
  __shared__ __align__(16) unsigned short Vs[2][64][76];   // Vs[buf][d][key]

  const int z   = blockIdx.z;
  const int g1  = (z >= 4);
  const int dil = g1 ? 2 : 1;
  const int off = g1 ? 1 : 0;
  const long segb = g1 ? (long)(z - 4) * 4096 : (long)z * 2048;
  const int h   = (g1 ? 8 : 0) + blockIdx.y;
  const int h64 = h * 64;

  const int bx   = (int)blockIdx.x;   // 0..15
  const int tid  = threadIdx.x;       // 0..127
  const int lane = tid & 63;
  const int w    = tid >> 6;          // wave 0/1: rows w*32..w*32+31 of the half
  const int q5   = lane & 31;
  const int hh   = lane >> 5;

  const int srow = tid >> 1;
  const int sc   = (tid & 1) * 32;

#pragma unroll
  for (int ph = 0; ph < 2; ++ph) {
    const int hf = ph ? bx : 31 - bx;   // half-tile index 0..31 (paired, equal work)
    const int qq = hf*64 + w*32 + q5;
    const long qrow = segb + off + (long)dil * qq;

    bf16x8 qf[4];
    {
      const unsigned short* qsrc = Qp + qrow * EMB + h64 + 8*hh;
#pragma unroll
      for (int s = 0; s < 4; ++s) qf[s] = *(const bf16x8*)(qsrc + 16*s);
    }

    float l_run = 0.f;
    f32x16 o0, o1;
#pragma unroll
    for (int r = 0; r < 16; ++r) { o0[r] = 0.f; o1[r] = 0.f; }

    us8 kr0, kr1, kr2, kr3, vr0, vr1, vr2, vr3;
    // prologue: stage tile 0
    {
      const long gk = segb + off + (long)dil * srow;
      const unsigned short* ksrc = Kp + gk*EMB + h64 + sc;
      kr0 = *(const us8*)ksrc;        kr1 = *(const us8*)(ksrc + 8);
      kr2 = *(const us8*)(ksrc + 16); kr3 = *(const us8*)(ksrc + 24);
      const unsigned short* vsrc = Vt + (long)(h64 + srow)*N_TOK + segb + sc;
      vr0 = *(const us8*)vsrc;        vr1 = *(const us8*)(vsrc + 8);
      vr2 = *(const us8*)(vsrc + 16); vr3 = *(const us8*)(vsrc + 24);
      *(us8*)&Ks[0][srow][sc]    = kr0; *(us8*)&Ks[0][srow][sc+8]  = kr1;
      *(us8*)&Ks[0][srow][sc+16] = kr2; *(us8*)&Ks[0][srow][sc+24] = kr3;
      *(us8*)&Vs[0][srow][sc]    = vr0; *(us8*)&Vs[0][srow][sc+8]  = vr1;
      *(us8*)&Vs[0][srow][sc+16] = vr2; *(us8*)&Vs[0][srow][sc+24] = vr3;
    }
    __syncthreads();
    int cur = 0;

    // ---- steady loop: tiles 0..hf-1, branch/mask-free ----
    for (int j = 0; j < hf; ++j) {
      // issue next-tile loads early (latency hides under compute)
      {
        const long gk = segb + off + (long)dil * ((j+1)*64 + srow);
        const unsigned short* ksrc = Kp + gk*EMB + h64 + sc;
        kr0 = *(const us8*)ksrc;        kr1 = *(const us8*)(ksrc + 8);
        kr2 = *(const us8*)(ksrc + 16); kr3 = *(const us8*)(ksrc + 24);
        const unsigned short* vsrc = Vt + (long)(h64 + srow)*N_TOK + segb + (j+1)*64 + sc;
        vr0 = *(const us8*)vsrc;        vr1 = *(const us8*)(vsrc + 8);
        vr2 = *(const us8*)(vsrc + 16); vr3 = *(const us8*)(vsrc + 24);
      }

      f32x16 sa0, sa1;
#pragma unroll
      for (int r = 0; r < 16; ++r) { sa0[r] = 0.f; sa1[r] = 0.f; }
      __builtin_amdgcn_s_setprio(1);
#pragma unroll
      for (int s = 0; s < 4; ++s) {
        bf16x8 ka = *(const bf16x8*)&Ks[cur][q5][16*s + 8*hh];
        sa0 = mfma32(ka, qf[s], sa0);
      }
#pragma unroll
      for (int s = 0; s < 4; ++s) {
        bf16x8 kb = *(const bf16x8*)&Ks[cur][32 + q5][16*s + 8*hh];
        sa1 = mfma32(kb, qf[s], sa1);
      }
      __builtin_amdgcn_s_setprio(0);

      float sv[32];
#pragma unroll
      for (int r = 0; r < 16; ++r) { sv[r] = sa0[r]; sv[16+r] = sa1[r]; }

      float ps0 = 0.f, ps1 = 0.f, ps2 = 0.f, ps3 = 0.f;
#pragma unroll
      for (int i = 0; i < 32; i += 4) {
        float e0 = exp2f(sv[i]);   sv[i]   = e0; ps0 += e0;
        float e1 = exp2f(sv[i+1]); sv[i+1] = e1; ps1 += e1;
        float e2 = exp2f(sv[i+2]); sv[i+2] = e2; ps2 += e2;
        float e3 = exp2f(sv[i+3]); sv[i+3] = e3; ps3 += e3;
      }
      float psum = (ps0 + ps1) + (ps2 + ps3);
      {
        union { float f; unsigned int u; } pc; pc.f = psum;
        uint2v ps = __builtin_amdgcn_permlane32_swap(pc.u, pc.u, false, false);
        union { unsigned int u; float f; } a0, a1;
        a0.u = ps[0]; a1.u = ps[1];
        psum = a0.f + a1.f;
      }
      l_run += psum;

#pragma unroll
      for (int ks = 0; ks < 4; ++ks) {
        const unsigned int pk0 = cvtpk(sv[8*ks+0], sv[8*ks+1]);
        const unsigned int pk1 = cvtpk(sv[8*ks+2], sv[8*ks+3]);
        const unsigned int pk2 = cvtpk(sv[8*ks+4], sv[8*ks+5]);
        const unsigned int pk3 = cvtpk(sv[8*ks+6], sv[8*ks+7]);
        uint2v s02 = __builtin_amdgcn_permlane32_swap(pk0, pk2, false, false);
        uint2v s13 = __builtin_amdgcn_permlane32_swap(pk1, pk3, false, false);
        union { unsigned int wd[4]; bf16x8 v; } pu;
        pu.wd[0] = s02[0];
        pu.wd[1] = s13[0];
        pu.wd[2] = s02[1];
        pu.wd[3] = s13[1];
        __builtin_amdgcn_s_setprio(1);
        bf16x8 va = *(const bf16x8*)&Vs[cur][q5][16*ks + 8*hh];
        o0 = mfma32(va, pu.v, o0);
        bf16x8 vb = *(const bf16x8*)&Vs[cur][32 + q5][16*ks + 8*hh];
        o1 = mfma32(vb, pu.v, o1);
        __builtin_amdgcn_s_setprio(0);
      }

      // write-late: next tile into the other buffer
      *(us8*)&Ks[cur^1][srow][sc]    = kr0; *(us8*)&Ks[cur^1][srow][sc+8]  = kr1;
      *(us8*)&Ks[cur^1][srow][sc+16] = kr2; *(us8*)&Ks[cur^1][srow][sc+24] = kr3;
      *(us8*)&Vs[cur^1][srow][sc]    = vr0; *(us8*)&Vs[cur^1][srow][sc+8]  = vr1;
      *(us8*)&Vs[cur^1][srow][sc+16] = vr2; *(us8*)&Vs[cur^1][srow][sc+24] = vr3;
      __syncthreads();
      cur ^= 1;
    }

    // ---- peeled diagonal tile (j == hf), buffer cur ----
    {
      const int j = hf;
      f32x16 sa0, sa1;
#pragma unroll
      for (int r = 0; r < 16; ++r) { sa0[r] = 0.f; sa1[r] = 0.f; }
      __builtin_amdgcn_s_setprio(1);
#pragma unroll
      for (int s = 0; s < 4; ++s) {
        bf16x8 ka = *(const bf16x8*)&Ks[cur][q5][16*s + 8*hh];
        sa0 = mfma32(ka, qf[s], sa0);
      }
#pragma unroll
      for (int s = 0; s < 4; ++s) {
        bf16x8 kb = *(const bf16x8*)&Ks[cur][32 + q5][16*s + 8*hh];
        sa1 = mfma32(kb, qf[s], sa1);
      }
      __builtin_amdgcn_s_setprio(0);

      const bool do_kb1 = (w == 1);

      float sv[32];
#pragma unroll
      for (int r = 0; r < 16; ++r) {
        const int kof = (r&3) + 8*(r>>2);
        float v = sa0[r];
        if (j*64 + kof + 4*hh > qq) v = -1e30f;
        sv[r] = v;
      }
      if (do_kb1) {
#pragma unroll
        for (int r = 0; r < 16; ++r) {
          const int kof = (r&3) + 8*(r>>2);
          float v = sa1[r];
          if (j*64 + 32 + kof + 4*hh > qq) v = -1e30f;
          sv[16+r] = v;
        }
      }

      float ps0 = 0.f, ps1 = 0.f, ps2 = 0.f, ps3 = 0.f;
#pragma unroll
      for (int i = 0; i < 16; i += 4) {
        float e0 = exp2f(sv[i]);   sv[i]   = e0; ps0 += e0;
        float e1 = exp2f(sv[i+1]); sv[i+1] = e1; ps1 += e1;
        float e2 = exp2f(sv[i+2]); sv[i+2] = e2; ps2 += e2;
        float e3 = exp2f(sv[i+3]); sv[i+3] = e3; ps3 += e3;
      }
      if (do_kb1) {
#pragma unroll
        for (int i = 16; i < 32; i += 4) {
          float e0 = exp2f(sv[i]);   sv[i]   = e0; ps0 += e0;
          float e1 = exp2f(sv[i+1]); sv[i+1] = e1; ps1 += e1;
          float e2 = exp2f(sv[i+2]); sv[i+2] = e2; ps2 += e2;
          float e3 = exp2f(sv[i+3]); sv[i+3] = e3; ps3 += e3;
        }
      }
      float psum = (ps0 + ps1) + (ps2 + ps3);
      {
        union { float f; unsigned int u; } pc; pc.f = psum;
        uint2v ps = __builtin_amdgcn_permlane32_swap(pc.u, pc.u, false, false);
        union { unsigned int u; float f; } a0, a1;
        a0.u = ps[0]; a1.u = ps[1];
        psum = a0.f + a1.f;
      }
      l_run += psum;

#pragma unroll
      for (int ks = 0; ks < 4; ++ks) {
        if (ks >= 2 && !do_kb1) continue;
        const unsigned int pk0 = cvtpk(sv[8*ks+0], sv[8*ks+1]);
        const unsigned int pk1 = cvtpk(sv[8*ks+2], sv[8*ks+3]);
        const unsigned int pk2 = cvtpk(sv[8*ks+4], sv[8*ks+5]);
        const unsigned int pk3 = cvtpk(sv[8*ks+6], sv[8*ks+7]);
        uint2v s02 = __builtin_amdgcn_permlane32_swap(pk0, pk2, false, false);
        uint2v s13 = __builtin_amdgcn_permlane32_swap(pk1, pk3, false, false);
        union { unsigned int wd[4]; bf16x8 v; } pu;
        pu.wd[0] = s02[0];
        pu.wd[1] = s13[0];
        pu.wd[2] = s02[1];
        pu.wd[3] = s13[1];
        __builtin_amdgcn_s_setprio(1);
        bf16x8 va = *(const bf16x8*)&Vs[cur][q5][16*ks + 8*hh];
        o0 = mfma32(va, pu.v, o0);
        bf16x8 vb = *(const bf16x8*)&Vs[cur][32 + q5][16*ks + 8*hh];
        o1 = mfma32(vb, pu.v, o1);
        __builtin_amdgcn_s_setprio(0);
      }
    }
    __syncthreads();   // protect buffer before next phase's prologue staging

    // epilogue for this phase
    {
      const float inv = 1.f / l_run;
      unsigned short* dst = AO + qrow * EMB + h64;
#pragma unroll
      for (int r = 0; r < 16; ++r) {
        const int d = (r&3) + 8*(r>>2) + 4*hh;
        dst[d]      = f2bf(o0[r] * inv);
        dst[32 + d] = f2bf(o1[r] * inv);
      }
    }
  }
}

// ---------------- output projection: m97 structure ----------------
__global__ __launch_bounds__(256) void gemm_out4(
    const unsigned short* __restrict__ A, const unsigned short* __restrict__ Wb,
    const float* __restrict__ bias, float* __restrict__ outp)
{
  __shared__ __align__(16) unsigned short As[128 * 32];
  __shared__ __align__(16) unsigned short Bs[128 * 32];

  const int lin  = blockIdx.x;
  const int work = (lin & 7) * 64 + (lin >> 3);
  const long brow = (long)(work >> 3) * 128;
  const long bcol = (long)(work & 7) * 128;

  const int tid  = threadIdx.x;
  const int lane = tid & 63;
  const int w    = tid >> 6;
  const int wrb  = (w >> 1) * 64;
  const int wcb  = (w & 1) * 64;
  const int r16  = lane & 15;
  const int kq   = (lane >> 4) * 8;
  const int rq   = (lane >> 4) * 4;

  const int srow = lane >> 2;
  const int scol = (lane & 3) * 8;
  const unsigned short* Ag0 = A  + (brow + w*32      + srow) * (long)EMB + scol;
  const unsigned short* Ag1 = A  + (brow + w*32 + 16 + srow) * (long)EMB + scol;
  const unsigned short* Bg0 = Wb + (bcol + w*32      + srow) * (long)EMB + scol;
  const unsigned short* Bg1 = Wb + (bcol + w*32 + 16 + srow) * (long)EMB + scol;
  unsigned short* Al0 = As + w * 1024;
  unsigned short* Al1 = As + w * 1024 + 512;
  unsigned short* Bl0 = Bs + w * 1024;
  unsigned short* Bl1 = Bs + w * 1024 + 512;

  const f32x4 zz = {0.f, 0.f, 0.f, 0.f};
  f32x4 acc[4][4];
#pragma unroll
  for (int i = 0; i < 4; ++i)
#pragma unroll
    for (int j = 0; j < 4; ++j) acc[i][j] = zz;

  for (int k0 = 0; k0 < EMB; k0 += 32) {
    __syncthreads();
    gload16(Ag0 + k0, Al0);
    gload16(Ag1 + k0, Al1);
    gload16(Bg0 + k0, Bl0);
    gload16(Bg1 + k0, Bl1);
    __syncthreads();

    bf16x8 av[4], bv_[4];
#pragma unroll
    for (int mi = 0; mi < 4; ++mi) av[mi]  = *(const bf16x8*)&As[(wrb + mi*16 + r16)*32 + kq];
#pragma unroll
    for (int ni = 0; ni < 4; ++ni) bv_[ni] = *(const bf16x8*)&Bs[(wcb + ni*16 + r16)*32 + kq];
#pragma unroll
    for (int mi = 0; mi < 4; ++mi)
#pragma unroll
      for (int ni = 0; ni < 4; ++ni)
        acc[mi][ni] = mfma16(av[mi], bv_[ni], acc[mi][ni]);
  }

#pragma unroll
  for (int ni = 0; ni < 4; ++ni) {
    const long col = bcol + wcb + ni*16 + r16;
    const float bval = bias[col];
#pragma unroll
    for (int mi = 0; mi < 4; ++mi)
#pragma unroll
      for (int jr = 0; jr < 4; ++jr) {
        const long row = brow + wrb + mi*16 + rq + jr;
        outp[row * (long)EMB + col] = acc[mi][ni][jr] + bval;
      }
  }
}

extern "C" void kernel_launch(void* const* d_in, const int* in_sizes, int n_in,
                              void* d_out, int out_size, void* d_ws, size_t ws_size,
                              hipStream_t stream) {
  const float* query = (const float*)d_in[0];
  const float* key_  = (const float*)d_in[1];
  const float* value = (const float*)d_in[2];
  const float* Wq = (const float*)d_in[3];
  const float* bq = (const float*)d_in[4];
  const float* Wk = (const float*)d_in[5];
  const float* bk = (const float*)d_in[6];
  const float* Wv = (const float*)d_in[7];
  const float* bv = (const float*)d_in[8];
  const float* Wo = (const float*)d_in[9];
  const float* bo = (const float*)d_in[10];

  unsigned short* Qp  = (unsigned short*)d_ws;
  unsigned short* Kp  = Qp + (size_t)N_TOK * EMB;
  unsigned short* Vt  = Kp + (size_t)N_TOK * EMB;   // [EMB][N_TOK], group1 token-remapped
  unsigned short* Wb  = Vt + (size_t)N_TOK * EMB;   // Wq,Wk,Wv,Wo bf16 (8 MB)
  unsigned short* S   = Wb + (size_t)4 * EMB * EMB; // X_v, then AO
  unsigned short* Xbq = (unsigned short*)d_out;     // scratch in d_out
  unsigned short* Xbk = Xbq + (size_t)N_TOK * EMB;
  unsigned short* Xbv = S;
  unsigned short* AO  = S;
  unsigned short* Wob = Wb + (size_t)3 * EMB * EMB;

  dim3 blk(256);

  hipLaunchKernelGGL(convall, dim3(7168), blk, 0, stream,
                     query, key_, value, Wq, Wk, Wv, Wo, Xbq, Xbk, Xbv, Wb);

  hipLaunchKernelGGL(qkv_gemm7, dim3(512, 1, 3), blk, 0, stream,
                     Xbq, Xbk, Xbv, Wb, bq, bk, bv, Qp, Kp, Vt);

  hipLaunchKernelGGL(zerog1, dim3(1024), blk, 0, stream, AO);

  hipLaunchKernelGGL(attn_dilated12, dim3(16, 8, 6), dim3(128), 0, stream, Qp, Kp, Vt, AO);

  hipLaunchKernelGGL(gemm_out4, dim3(512), blk, 0, stream, AO, Wob, bo, (float*)d_out);
}